// Round 1
// baseline (605.038 us; speedup 1.0000x reference)
//
#include <hip/hip_runtime.h>
#include <hip/hip_bf16.h>

#define N_NODES 50000
#define N_EDGES 800000
#define NPAD    50048   // 391*128

typedef __attribute__((ext_vector_type(8))) short bf16x8;
typedef __attribute__((ext_vector_type(8))) unsigned short u16x8;
typedef __attribute__((ext_vector_type(4))) float f32x4;

__device__ __forceinline__ unsigned short f2bf(float f) {
  union { float f; unsigned u; } x; x.f = f;
  unsigned r = x.u + 0x7fffu + ((x.u >> 16) & 1u);
  return (unsigned short)(r >> 16);
}
__device__ __forceinline__ float bf2f(unsigned short u) {
  union { unsigned u; float f; } x; x.u = ((unsigned)u) << 16;
  return x.f;
}

// ---------------- CSR build ----------------
__global__ void hist_kernel(const int* __restrict__ dst, int* __restrict__ counts, int E) {
  int e = blockIdx.x * 256 + threadIdx.x;
  if (e < E) atomicAdd(&counts[dst[e]], 1);
}

__global__ __launch_bounds__(1024) void scan_kernel(const int* __restrict__ counts,
                                                    int* __restrict__ offsets,
                                                    int* __restrict__ cursor, int n, int Etot) {
  __shared__ int sm[1024];
  __shared__ int carry_s;
  if (threadIdx.x == 0) carry_s = 0;
  __syncthreads();
  for (int base = 0; base < n; base += 1024) {
    int i = base + threadIdx.x;
    int v = (i < n) ? counts[i] : 0;
    int cb = carry_s;
    __syncthreads();
    sm[threadIdx.x] = v;
    __syncthreads();
    for (int off = 1; off < 1024; off <<= 1) {
      int t = (threadIdx.x >= off) ? sm[threadIdx.x - off] : 0;
      __syncthreads();
      sm[threadIdx.x] += t;
      __syncthreads();
    }
    if (i < n) { int ex = cb + sm[threadIdx.x] - v; offsets[i] = ex; cursor[i] = ex; }
    __syncthreads();
    if (threadIdx.x == 0) carry_s = cb + sm[1023];
    __syncthreads();
  }
  if (threadIdx.x == 0) offsets[n] = Etot;
}

__global__ void scatter_kernel(const int* __restrict__ src, const int* __restrict__ dst,
                               int* __restrict__ cursor, int* __restrict__ csr_src, int E) {
  int e = blockIdx.x * 256 + threadIdx.x;
  if (e < E) {
    int pos = atomicAdd(&cursor[dst[e]], 1);
    csr_src[pos] = src[e];
  }
}

// ---------------- packing / conversion ----------------
__global__ void convert_x_kernel(const float* __restrict__ x, unsigned short* __restrict__ xb,
                                 int total_real, int total_pad) {
  long i = ((long)blockIdx.x * 256 + threadIdx.x) * 4;
  if (i >= total_pad) return;
  ushort4 o;
  if (i < total_real) {
    float4 v = *(const float4*)&x[i];
    o.x = f2bf(v.x); o.y = f2bf(v.y); o.z = f2bf(v.z); o.w = f2bf(v.w);
  } else {
    o.x = 0; o.y = 0; o.z = 0; o.w = 0;
  }
  *(ushort4*)&xb[i] = o;
}

__global__ void pack_w1_kernel(const float* __restrict__ Wq, const float* __restrict__ Wk,
                               const float* __restrict__ Wv, const float* __restrict__ Ws,
                               const float* __restrict__ bq, const float* __restrict__ bk,
                               const float* __restrict__ bv, const float* __restrict__ bs_,
                               unsigned short* __restrict__ wbt, float* __restrict__ bias1) {
  int idx = blockIdx.x * 256 + threadIdx.x;
  if (idx >= 1024 * 384) return;
  int n = idx / 384, k = idx - n * 384;
  int blk = n >> 8, cc = n & 255;
  const float* W = (blk == 0) ? Wq : (blk == 1) ? Wk : (blk == 2) ? Wv : Ws;
  wbt[idx] = f2bf(W[(long)k * 256 + cc]);   // wbt[n][k] = W[k][cc]  (transposed)
  if (k == 0) {
    const float* b = (blk == 0) ? bq : (blk == 1) ? bk : (blk == 2) ? bv : bs_;
    bias1[n] = b[cc];
  }
}

__global__ void pack_w2_kernel(const float* __restrict__ Wq, const float* __restrict__ Wk,
                               const float* __restrict__ Wv, const float* __restrict__ Ws,
                               const float* __restrict__ bq, const float* __restrict__ bk,
                               const float* __restrict__ bv, const float* __restrict__ bs_,
                               float* __restrict__ w2t, float* __restrict__ bias2) {
  int idx = blockIdx.x * 256 + threadIdx.x;
  if (idx >= 20 * 256) return;
  int c = idx / 256, k = idx - c * 256;
  int blk = c / 5, cc = c - blk * 5;
  const float* W = (blk == 0) ? Wq : (blk == 1) ? Wk : (blk == 2) ? Wv : Ws;
  w2t[idx] = W[(long)k * 5 + cc];           // w2t[c][k] = W[k][cc]
  if (k == 0) {
    const float* b = (blk == 0) ? bq : (blk == 1) ? bk : (blk == 2) ? bv : bs_;
    bias2[c] = b[cc];
  }
}

// ---------------- layer-1 fused QKVS GEMM (bf16 MFMA) ----------------
// Y[NPAD][1024] = xb[NPAD][384] @ W[384][1024] + bias ; cols 0-255->q(bf16),
// 256-511->k(bf16), 512-767->v(fp32), 768-1023->skip(fp32)
__global__ __launch_bounds__(256) void gemm1_kernel(
    const unsigned short* __restrict__ xb, const unsigned short* __restrict__ wbt,
    const float* __restrict__ bias,
    unsigned short* __restrict__ qb, unsigned short* __restrict__ kb,
    float* __restrict__ vf, float* __restrict__ s1) {
  __shared__ unsigned short As[128 * 32];
  __shared__ unsigned short Bs[128 * 32];
  int tid = threadIdx.x;
  long m0 = (long)blockIdx.x * 128;
  int n0 = blockIdx.y * 128;
  int w = tid >> 6, l = tid & 63;
  int wr = (w >> 1) * 64, wc = (w & 1) * 64;
  int lr = l & 15, lk = (l >> 4) * 8;
  f32x4 acc[4][4] = {};
  int r = tid >> 2;
  int c8 = (tid & 3) * 8;
  const unsigned short* ga = xb + (m0 + r) * 384 + c8;
  const unsigned short* gb = wbt + (long)(n0 + r) * 384 + c8;
  for (int kt = 0; kt < 12; ++kt) {
    int ko = kt * 32;
    u16x8 a0 = *(const u16x8*)(ga + ko);
    u16x8 a1 = *(const u16x8*)(ga + 64 * 384 + ko);
    u16x8 b0 = *(const u16x8*)(gb + ko);
    u16x8 b1 = *(const u16x8*)(gb + 64 * 384 + ko);
    __syncthreads();
    *(u16x8*)&As[r * 32 + c8] = a0;
    *(u16x8*)&As[(r + 64) * 32 + c8] = a1;
    *(u16x8*)&Bs[r * 32 + c8] = b0;
    *(u16x8*)&Bs[(r + 64) * 32 + c8] = b1;
    __syncthreads();
    bf16x8 af[4], bfv[4];
#pragma unroll
    for (int mf = 0; mf < 4; ++mf) af[mf] = *(const bf16x8*)&As[(wr + mf * 16 + lr) * 32 + lk];
#pragma unroll
    for (int nf = 0; nf < 4; ++nf) bfv[nf] = *(const bf16x8*)&Bs[(wc + nf * 16 + lr) * 32 + lk];
#pragma unroll
    for (int mf = 0; mf < 4; ++mf)
#pragma unroll
      for (int nf = 0; nf < 4; ++nf)
        acc[mf][nf] = __builtin_amdgcn_mfma_f32_16x16x32_bf16(af[mf], bfv[nf], acc[mf][nf], 0, 0, 0);
  }
  int dblk = n0 >> 8;  // 128-col tiles never straddle a 256 boundary
#pragma unroll
  for (int nf = 0; nf < 4; ++nf) {
    int col = n0 + wc + nf * 16 + lr;
    int cc = col & 255;
    float bv = bias[col];
#pragma unroll
    for (int mf = 0; mf < 4; ++mf) {
      long row = m0 + wr + mf * 16 + (l >> 4) * 4;
#pragma unroll
      for (int i = 0; i < 4; ++i) {
        float v = acc[mf][nf][i] + bv;
        long idx = (row + i) * 256 + cc;
        if (dblk == 0) qb[idx] = f2bf(v);
        else if (dblk == 1) kb[idx] = f2bf(v);
        else if (dblk == 2) vf[idx] = v;
        else s1[idx] = v;
      }
    }
  }
}

// ---------------- layer-1 fused attention aggregation ----------------
// one 64-lane wave per node; lane owns 4 channels; head = lane>>4
__global__ __launch_bounds__(256) void agg1_kernel(
    const unsigned short* __restrict__ qb, const unsigned short* __restrict__ kb,
    const float* __restrict__ vf, float* s1h,
    const int* __restrict__ offsets, const int* __restrict__ csr_src) {
  int w = threadIdx.x >> 6, l = threadIdx.x & 63;
  int n = blockIdx.x * 4 + w;
  if (n >= N_NODES) return;
  long rowq = (long)n * 256 + l * 4;
  ushort4 qu = *(const ushort4*)&qb[rowq];
  float q0 = bf2f(qu.x) * 0.125f, q1 = bf2f(qu.y) * 0.125f;
  float q2 = bf2f(qu.z) * 0.125f, q3 = bf2f(qu.w) * 0.125f;
  float a0 = 0.f, a1 = 0.f, a2 = 0.f, a3 = 0.f, se = 0.f;
  int i0 = offsets[n], i1 = offsets[n + 1];
  for (int i = i0; i < i1; ++i) {
    int s = csr_src[i];
    long rs = (long)s * 256 + l * 4;
    ushort4 ku = *(const ushort4*)&kb[rs];
    float p = q0 * bf2f(ku.x) + q1 * bf2f(ku.y) + q2 * bf2f(ku.z) + q3 * bf2f(ku.w);
    p += __shfl_xor(p, 1); p += __shfl_xor(p, 2);
    p += __shfl_xor(p, 4); p += __shfl_xor(p, 8);
    float ee = __expf(p);
    float4 vv = *(const float4*)&vf[rs];
    se += ee;
    a0 += ee * vv.x; a1 += ee * vv.y; a2 += ee * vv.z; a3 += ee * vv.w;
  }
  float inv = 1.0f / (se + 1e-16f);
  float4 sv = *(const float4*)&s1h[rowq];
  float4 rr;
  rr.x = fmaxf(a0 * inv + sv.x, 0.f);
  rr.y = fmaxf(a1 * inv + sv.y, 0.f);
  rr.z = fmaxf(a2 * inv + sv.z, 0.f);
  rr.w = fmaxf(a3 * inv + sv.w, 0.f);
  *(float4*)&s1h[rowq] = rr;   // h = relu(attn + skip), in place
}

// ---------------- layer-2 linear (h[256] -> 20 outs per row) ----------------
__global__ __launch_bounds__(256) void lin2_kernel(const float* __restrict__ h,
                                                   const float* __restrict__ w2t,
                                                   const float* __restrict__ bias2,
                                                   float* __restrict__ qkvs2) {
  __shared__ float ws[20 * 256];
  __shared__ float bs[20];
  for (int i = threadIdx.x; i < 20 * 256; i += 256) ws[i] = w2t[i];
  if (threadIdx.x < 20) bs[threadIdx.x] = bias2[threadIdx.x];
  __syncthreads();
  int w = threadIdx.x >> 6, l = threadIdx.x & 63;
  int n = blockIdx.x * 4 + w;
  if (n >= N_NODES) return;
  float4 hv = *(const float4*)&h[(long)n * 256 + l * 4];
  float myout = 0.f;
#pragma unroll
  for (int c = 0; c < 20; ++c) {
    float4 wv = *(const float4*)&ws[c * 256 + l * 4];
    float pp = hv.x * wv.x + hv.y * wv.y + hv.z * wv.z + hv.w * wv.w;
    pp += __shfl_xor(pp, 1);  pp += __shfl_xor(pp, 2);  pp += __shfl_xor(pp, 4);
    pp += __shfl_xor(pp, 8);  pp += __shfl_xor(pp, 16); pp += __shfl_xor(pp, 32);
    if (l == c) myout = pp + bs[c];
  }
  if (l < 20) qkvs2[(long)n * 20 + l] = myout;
}

// ---------------- layer-2 fused attention (1 thread per node) ----------------
__global__ void agg2_kernel(const float* __restrict__ qkvs2,
                            const int* __restrict__ offsets, const int* __restrict__ csr_src,
                            float* __restrict__ out) {
  int n = blockIdx.x * 256 + threadIdx.x;
  if (n >= N_NODES) return;
  const float* bn = &qkvs2[(long)n * 20];
  const float is5 = 0.4472135954999579f;  // 1/sqrt(5)
  float q[5], acc[5] = {0, 0, 0, 0, 0}, se = 0.f;
#pragma unroll
  for (int c = 0; c < 5; ++c) q[c] = bn[c] * is5;
  int i0 = offsets[n], i1 = offsets[n + 1];
  for (int i = i0; i < i1; ++i) {
    int s = csr_src[i];
    const float* bsrc = &qkvs2[(long)s * 20];
    float lg = q[0] * bsrc[5] + q[1] * bsrc[6] + q[2] * bsrc[7] + q[3] * bsrc[8] + q[4] * bsrc[9];
    float ee = __expf(lg);
    se += ee;
    acc[0] += ee * bsrc[10]; acc[1] += ee * bsrc[11]; acc[2] += ee * bsrc[12];
    acc[3] += ee * bsrc[13]; acc[4] += ee * bsrc[14];
  }
  float inv = 1.f / (se + 1e-16f);
#pragma unroll
  for (int c = 0; c < 5; ++c) out[(long)n * 5 + c] = acc[c] * inv + bn[15 + c];
}

// ---------------- launch ----------------
extern "C" void kernel_launch(void* const* d_in, const int* in_sizes, int n_in,
                              void* d_out, int out_size, void* d_ws, size_t ws_size,
                              hipStream_t stream) {
  (void)in_sizes; (void)n_in; (void)out_size; (void)ws_size;
  const float* x   = (const float*)d_in[0];
  const int* eidx  = (const int*)d_in[1];
  const int* esrc  = eidx;
  const int* edst  = eidx + N_EDGES;
  const float* Wq1 = (const float*)d_in[2];  const float* bq1 = (const float*)d_in[3];
  const float* Wk1 = (const float*)d_in[4];  const float* bk1 = (const float*)d_in[5];
  const float* Wv1 = (const float*)d_in[6];  const float* bv1 = (const float*)d_in[7];
  const float* Ws1 = (const float*)d_in[8];  const float* bs1 = (const float*)d_in[9];
  const float* Wq2 = (const float*)d_in[10]; const float* bq2 = (const float*)d_in[11];
  const float* Wk2 = (const float*)d_in[12]; const float* bk2 = (const float*)d_in[13];
  const float* Wv2 = (const float*)d_in[14]; const float* bv2 = (const float*)d_in[15];
  const float* Ws2 = (const float*)d_in[16]; const float* bs2 = (const float*)d_in[17];

  char* p = (char*)d_ws;
  auto take = [&](size_t bytes) { char* r = p; p += (bytes + 255) & ~(size_t)255; return r; };
  unsigned short* xb  = (unsigned short*)take((size_t)NPAD * 384 * 2);
  unsigned short* wbt = (unsigned short*)take((size_t)1024 * 384 * 2);
  float* bias1        = (float*)take(1024 * 4);
  unsigned short* qb  = (unsigned short*)take((size_t)NPAD * 256 * 2);
  unsigned short* kb  = (unsigned short*)take((size_t)NPAD * 256 * 2);
  float* vf           = (float*)take((size_t)NPAD * 256 * 4);
  float* s1h          = (float*)take((size_t)NPAD * 256 * 4);
  float* w2t          = (float*)take(20 * 256 * 4);
  float* bias2        = (float*)take(32 * 4);
  float* qkvs2        = (float*)take((size_t)NPAD * 20 * 4);
  int* counts         = (int*)take((size_t)N_NODES * 4);
  int* offsets        = (int*)take((size_t)(N_NODES + 1) * 4);
  int* cursor         = (int*)take((size_t)N_NODES * 4);
  int* csr_src        = (int*)take((size_t)N_EDGES * 4);

  hipMemsetAsync(counts, 0, (size_t)N_NODES * 4, stream);
  hist_kernel<<<(N_EDGES + 255) / 256, 256, 0, stream>>>(edst, counts, N_EDGES);
  scan_kernel<<<1, 1024, 0, stream>>>(counts, offsets, cursor, N_NODES, N_EDGES);
  scatter_kernel<<<(N_EDGES + 255) / 256, 256, 0, stream>>>(esrc, edst, cursor, csr_src, N_EDGES);
  convert_x_kernel<<<(NPAD * 384 / 4 + 255) / 256, 256, 0, stream>>>(x, xb, N_NODES * 384, NPAD * 384);
  pack_w1_kernel<<<(1024 * 384 + 255) / 256, 256, 0, stream>>>(Wq1, Wk1, Wv1, Ws1, bq1, bk1, bv1, bs1, wbt, bias1);
  pack_w2_kernel<<<(20 * 256 + 255) / 256, 256, 0, stream>>>(Wq2, Wk2, Wv2, Ws2, bq2, bk2, bv2, bs2, w2t, bias2);
  gemm1_kernel<<<dim3(NPAD / 128, 8), 256, 0, stream>>>(xb, wbt, bias1, qb, kb, vf, s1h);
  agg1_kernel<<<(N_NODES + 3) / 4, 256, 0, stream>>>(qb, kb, vf, s1h, offsets, csr_src);
  lin2_kernel<<<(N_NODES + 3) / 4, 256, 0, stream>>>(s1h, w2t, bias2, qkvs2);
  agg2_kernel<<<(N_NODES + 255) / 256, 256, 0, stream>>>(qkvs2, offsets, csr_src, (float*)d_out);
}

// Round 2
// 409.371 us; speedup vs baseline: 1.4780x; 1.4780x over previous
//
#include <hip/hip_runtime.h>
#include <hip/hip_bf16.h>

#define N_NODES 50000
#define N_EDGES 800000
#define NPAD    50048   // 391*128
#define SCAN_B  196     // ceil(50000/256)

typedef __attribute__((ext_vector_type(8))) short bf16x8;
typedef __attribute__((ext_vector_type(8))) unsigned short u16x8;
typedef __attribute__((ext_vector_type(4))) float f32x4;

__device__ __forceinline__ unsigned short f2bf(float f) {
  union { float f; unsigned u; } x; x.f = f;
  unsigned r = x.u + 0x7fffu + ((x.u >> 16) & 1u);
  return (unsigned short)(r >> 16);
}
__device__ __forceinline__ float bf2f(unsigned short u) {
  union { unsigned u; float f; } x; x.u = ((unsigned)u) << 16;
  return x.f;
}

// ---------------- CSR build ----------------
__global__ void hist_kernel(const int* __restrict__ dst, int* __restrict__ counts, int E) {
  int e = blockIdx.x * 256 + threadIdx.x;
  if (e < E) atomicAdd(&counts[dst[e]], 1);
}

// 3-kernel exact prefix sum over counts[0..n)
__global__ __launch_bounds__(256) void scan1_kernel(const int* __restrict__ counts,
                                                    int* __restrict__ tmp, int* __restrict__ bsum, int n) {
  __shared__ int sm[256];
  int i = blockIdx.x * 256 + threadIdx.x;
  int v = (i < n) ? counts[i] : 0;
  sm[threadIdx.x] = v;
  __syncthreads();
  for (int off = 1; off < 256; off <<= 1) {
    int t = (threadIdx.x >= off) ? sm[threadIdx.x - off] : 0;
    __syncthreads();
    sm[threadIdx.x] += t;
    __syncthreads();
  }
  if (i < n) tmp[i] = sm[threadIdx.x] - v;           // exclusive within block
  if (threadIdx.x == 255) bsum[blockIdx.x] = sm[255]; // block total
}

__global__ __launch_bounds__(256) void scan2_kernel(const int* __restrict__ bsum,
                                                    int* __restrict__ bbase, int nb) {
  __shared__ int sm[256];
  int v = (threadIdx.x < nb) ? bsum[threadIdx.x] : 0;
  sm[threadIdx.x] = v;
  __syncthreads();
  for (int off = 1; off < 256; off <<= 1) {
    int t = (threadIdx.x >= off) ? sm[threadIdx.x - off] : 0;
    __syncthreads();
    sm[threadIdx.x] += t;
    __syncthreads();
  }
  if (threadIdx.x < nb) bbase[threadIdx.x] = sm[threadIdx.x] - v;
}

__global__ __launch_bounds__(256) void scan3_kernel(const int* __restrict__ tmp,
                                                    const int* __restrict__ bbase,
                                                    int* __restrict__ offsets, int* __restrict__ cursor,
                                                    int n, int E) {
  int i = blockIdx.x * 256 + threadIdx.x;
  if (i < n) {
    int o = tmp[i] + bbase[blockIdx.x];
    offsets[i] = o;
    cursor[i] = o;
  }
  if (i == 0) offsets[n] = E;
}

__global__ void scatter_kernel(const int* __restrict__ src, const int* __restrict__ dst,
                               int* __restrict__ cursor, int* __restrict__ csr_src, int E) {
  int e = blockIdx.x * 256 + threadIdx.x;
  if (e < E) {
    int pos = atomicAdd(&cursor[dst[e]], 1);
    csr_src[pos] = src[e];
  }
}

// ---------------- packing / conversion ----------------
__global__ void convert_x_kernel(const float* __restrict__ x, unsigned short* __restrict__ xb,
                                 int total_real, int total_pad) {
  long i = ((long)blockIdx.x * 256 + threadIdx.x) * 4;
  if (i >= total_pad) return;
  ushort4 o;
  if (i < total_real) {
    float4 v = *(const float4*)&x[i];
    o.x = f2bf(v.x); o.y = f2bf(v.y); o.z = f2bf(v.z); o.w = f2bf(v.w);
  } else {
    o.x = 0; o.y = 0; o.z = 0; o.w = 0;
  }
  *(ushort4*)&xb[i] = o;
}

__global__ void pack_w1_kernel(const float* __restrict__ Wq, const float* __restrict__ Wk,
                               const float* __restrict__ Wv, const float* __restrict__ Ws,
                               const float* __restrict__ bq, const float* __restrict__ bk,
                               const float* __restrict__ bv, const float* __restrict__ bs_,
                               unsigned short* __restrict__ wbt, float* __restrict__ bias1) {
  int idx = blockIdx.x * 256 + threadIdx.x;
  if (idx >= 1024 * 384) return;
  int n = idx / 384, k = idx - n * 384;
  int blk = n >> 8, cc = n & 255;
  const float* W = (blk == 0) ? Wq : (blk == 1) ? Wk : (blk == 2) ? Wv : Ws;
  wbt[idx] = f2bf(W[(long)k * 256 + cc]);   // wbt[n][k] = W[k][cc]  (transposed)
  if (k == 0) {
    const float* b = (blk == 0) ? bq : (blk == 1) ? bk : (blk == 2) ? bv : bs_;
    bias1[n] = b[cc];
  }
}

__global__ void pack_w2_kernel(const float* __restrict__ Wq, const float* __restrict__ Wk,
                               const float* __restrict__ Wv, const float* __restrict__ Ws,
                               const float* __restrict__ bq, const float* __restrict__ bk,
                               const float* __restrict__ bv, const float* __restrict__ bs_,
                               float* __restrict__ w2t, float* __restrict__ bias2) {
  int idx = blockIdx.x * 256 + threadIdx.x;
  if (idx >= 20 * 256) return;
  int c = idx / 256, k = idx - c * 256;
  int blk = c / 5, cc = c - blk * 5;
  const float* W = (blk == 0) ? Wq : (blk == 1) ? Wk : (blk == 2) ? Wv : Ws;
  w2t[idx] = W[(long)k * 5 + cc];           // w2t[c][k] = W[k][cc]
  if (k == 0) {
    const float* b = (blk == 0) ? bq : (blk == 1) ? bk : (blk == 2) ? bv : bs_;
    bias2[c] = b[cc];
  }
}

// ---------------- layer-1 fused QKVS GEMM (bf16 MFMA) ----------------
// Y[NPAD][1024] = xb[NPAD][384] @ W[384][1024] + bias
// col block 0->q, 1->k, 2->v, 3->skip   (all bf16 out)
// BM=128, BN=256, BK=32, 512 threads (8 waves as 2x4 of 64x64)
__global__ __launch_bounds__(512) void gemm1_kernel(
    const unsigned short* __restrict__ xb, const unsigned short* __restrict__ wbt,
    const float* __restrict__ bias,
    unsigned short* __restrict__ qb, unsigned short* __restrict__ kb,
    unsigned short* __restrict__ vb, unsigned short* __restrict__ s1b) {
  __shared__ unsigned short As[128 * 32];
  __shared__ unsigned short Bs[256 * 32];
  int tid = threadIdx.x;
  long m0 = (long)blockIdx.x * 128;
  int n0 = blockIdx.y * 256;
  int w = tid >> 6, l = tid & 63;
  int wr = (w >> 2) * 64, wc = (w & 3) * 64;
  int lr = l & 15, lk = (l >> 4) * 8;
  f32x4 acc[4][4] = {};
  int rA = tid >> 2, cA = (tid & 3) * 8;
  int rB = tid >> 1, cB = (tid & 1) * 16;
  const unsigned short* ga = xb + (m0 + rA) * 384 + cA;
  const unsigned short* gb = wbt + (long)(n0 + rB) * 384 + cB;
  for (int kt = 0; kt < 12; ++kt) {
    int ko = kt * 32;
    u16x8 a0 = *(const u16x8*)(ga + ko);
    u16x8 b0 = *(const u16x8*)(gb + ko);
    u16x8 b1 = *(const u16x8*)(gb + ko + 8);
    __syncthreads();
    *(u16x8*)&As[rA * 32 + cA] = a0;
    *(u16x8*)&Bs[rB * 32 + cB] = b0;
    *(u16x8*)&Bs[rB * 32 + cB + 8] = b1;
    __syncthreads();
    bf16x8 af[4], bfv[4];
#pragma unroll
    for (int mf = 0; mf < 4; ++mf) af[mf] = *(const bf16x8*)&As[(wr + mf * 16 + lr) * 32 + lk];
#pragma unroll
    for (int nf = 0; nf < 4; ++nf) bfv[nf] = *(const bf16x8*)&Bs[(wc + nf * 16 + lr) * 32 + lk];
#pragma unroll
    for (int mf = 0; mf < 4; ++mf)
#pragma unroll
      for (int nf = 0; nf < 4; ++nf)
        acc[mf][nf] = __builtin_amdgcn_mfma_f32_16x16x32_bf16(af[mf], bfv[nf], acc[mf][nf], 0, 0, 0);
  }
  unsigned short* op = (blockIdx.y == 0) ? qb : (blockIdx.y == 1) ? kb : (blockIdx.y == 2) ? vb : s1b;
#pragma unroll
  for (int nf = 0; nf < 4; ++nf) {
    int col = n0 + wc + nf * 16 + lr;
    int cc = col & 255;
    float bv = bias[col];
#pragma unroll
    for (int mf = 0; mf < 4; ++mf) {
      long row = m0 + wr + mf * 16 + (l >> 4) * 4;
#pragma unroll
      for (int i = 0; i < 4; ++i) {
        op[(row + i) * 256 + cc] = f2bf(acc[mf][nf][i] + bv);
      }
    }
  }
}

// ---------------- layer-1 fused attention aggregation ----------------
// one 64-lane wave per node; lane owns 4 channels; head = lane>>4
// all of q/k/v/skip are bf16; h = relu(attn+skip) written bf16 in place of skip
__global__ __launch_bounds__(256) void agg1_kernel(
    const unsigned short* __restrict__ qb, const unsigned short* __restrict__ kb,
    const unsigned short* __restrict__ vb, unsigned short* s1b,
    const int* __restrict__ offsets, const int* __restrict__ csr_src) {
  int w = threadIdx.x >> 6, l = threadIdx.x & 63;
  int n = blockIdx.x * 4 + w;
  if (n >= N_NODES) return;
  long rowq = (long)n * 256 + l * 4;
  ushort4 qu = *(const ushort4*)&qb[rowq];
  float q0 = bf2f(qu.x) * 0.125f, q1 = bf2f(qu.y) * 0.125f;
  float q2 = bf2f(qu.z) * 0.125f, q3 = bf2f(qu.w) * 0.125f;
  float a0 = 0.f, a1 = 0.f, a2 = 0.f, a3 = 0.f, se = 0.f;
  int i0 = offsets[n], i1 = offsets[n + 1];
  int i = i0;
  for (; i + 1 < i1; i += 2) {
    int s0 = csr_src[i], s1 = csr_src[i + 1];
    long r0 = (long)s0 * 256 + l * 4;
    long r1 = (long)s1 * 256 + l * 4;
    ushort4 k0 = *(const ushort4*)&kb[r0];
    ushort4 k1 = *(const ushort4*)&kb[r1];
    ushort4 v0 = *(const ushort4*)&vb[r0];
    ushort4 v1 = *(const ushort4*)&vb[r1];
    float p0 = q0 * bf2f(k0.x) + q1 * bf2f(k0.y) + q2 * bf2f(k0.z) + q3 * bf2f(k0.w);
    float p1 = q0 * bf2f(k1.x) + q1 * bf2f(k1.y) + q2 * bf2f(k1.z) + q3 * bf2f(k1.w);
    p0 += __shfl_xor(p0, 1); p0 += __shfl_xor(p0, 2);
    p0 += __shfl_xor(p0, 4); p0 += __shfl_xor(p0, 8);
    p1 += __shfl_xor(p1, 1); p1 += __shfl_xor(p1, 2);
    p1 += __shfl_xor(p1, 4); p1 += __shfl_xor(p1, 8);
    float e0 = __expf(p0), e1 = __expf(p1);
    se += e0 + e1;
    a0 += e0 * bf2f(v0.x) + e1 * bf2f(v1.x);
    a1 += e0 * bf2f(v0.y) + e1 * bf2f(v1.y);
    a2 += e0 * bf2f(v0.z) + e1 * bf2f(v1.z);
    a3 += e0 * bf2f(v0.w) + e1 * bf2f(v1.w);
  }
  if (i < i1) {
    int s = csr_src[i];
    long rs = (long)s * 256 + l * 4;
    ushort4 ku = *(const ushort4*)&kb[rs];
    ushort4 vu = *(const ushort4*)&vb[rs];
    float p = q0 * bf2f(ku.x) + q1 * bf2f(ku.y) + q2 * bf2f(ku.z) + q3 * bf2f(ku.w);
    p += __shfl_xor(p, 1); p += __shfl_xor(p, 2);
    p += __shfl_xor(p, 4); p += __shfl_xor(p, 8);
    float ee = __expf(p);
    se += ee;
    a0 += ee * bf2f(vu.x); a1 += ee * bf2f(vu.y);
    a2 += ee * bf2f(vu.z); a3 += ee * bf2f(vu.w);
  }
  float inv = 1.0f / (se + 1e-16f);
  ushort4 sv = *(const ushort4*)&s1b[rowq];
  ushort4 hh;
  hh.x = f2bf(fmaxf(a0 * inv + bf2f(sv.x), 0.f));
  hh.y = f2bf(fmaxf(a1 * inv + bf2f(sv.y), 0.f));
  hh.z = f2bf(fmaxf(a2 * inv + bf2f(sv.z), 0.f));
  hh.w = f2bf(fmaxf(a3 * inv + bf2f(sv.w), 0.f));
  *(ushort4*)&s1b[rowq] = hh;   // h = relu(attn + skip), in place
}

// ---------------- layer-2 linear (h[256] -> 20 outs per row) ----------------
__global__ __launch_bounds__(256) void lin2_kernel(const unsigned short* __restrict__ hb,
                                                   const float* __restrict__ w2t,
                                                   const float* __restrict__ bias2,
                                                   float* __restrict__ qkvs2) {
  __shared__ float ws[20 * 256];
  __shared__ float bs[20];
  for (int i = threadIdx.x; i < 20 * 256; i += 256) ws[i] = w2t[i];
  if (threadIdx.x < 20) bs[threadIdx.x] = bias2[threadIdx.x];
  __syncthreads();
  int w = threadIdx.x >> 6, l = threadIdx.x & 63;
  int n = blockIdx.x * 4 + w;
  if (n >= N_NODES) return;
  ushort4 hu = *(const ushort4*)&hb[(long)n * 256 + l * 4];
  float h0 = bf2f(hu.x), h1 = bf2f(hu.y), h2 = bf2f(hu.z), h3 = bf2f(hu.w);
  float myout = 0.f;
#pragma unroll
  for (int c = 0; c < 20; ++c) {
    float4 wv = *(const float4*)&ws[c * 256 + l * 4];
    float pp = h0 * wv.x + h1 * wv.y + h2 * wv.z + h3 * wv.w;
    pp += __shfl_xor(pp, 1);  pp += __shfl_xor(pp, 2);  pp += __shfl_xor(pp, 4);
    pp += __shfl_xor(pp, 8);  pp += __shfl_xor(pp, 16); pp += __shfl_xor(pp, 32);
    if (l == c) myout = pp + bs[c];
  }
  if (l < 20) qkvs2[(long)n * 20 + l] = myout;
}

// ---------------- layer-2 fused attention (1 thread per node) ----------------
__global__ void agg2_kernel(const float* __restrict__ qkvs2,
                            const int* __restrict__ offsets, const int* __restrict__ csr_src,
                            float* __restrict__ out) {
  int n = blockIdx.x * 256 + threadIdx.x;
  if (n >= N_NODES) return;
  const float* bn = &qkvs2[(long)n * 20];
  const float is5 = 0.4472135954999579f;  // 1/sqrt(5)
  float q[5], acc[5] = {0, 0, 0, 0, 0}, se = 0.f;
#pragma unroll
  for (int c = 0; c < 5; ++c) q[c] = bn[c] * is5;
  int i0 = offsets[n], i1 = offsets[n + 1];
  for (int i = i0; i < i1; ++i) {
    int s = csr_src[i];
    const float* bsrc = &qkvs2[(long)s * 20];
    float lg = q[0] * bsrc[5] + q[1] * bsrc[6] + q[2] * bsrc[7] + q[3] * bsrc[8] + q[4] * bsrc[9];
    float ee = __expf(lg);
    se += ee;
    acc[0] += ee * bsrc[10]; acc[1] += ee * bsrc[11]; acc[2] += ee * bsrc[12];
    acc[3] += ee * bsrc[13]; acc[4] += ee * bsrc[14];
  }
  float inv = 1.f / (se + 1e-16f);
#pragma unroll
  for (int c = 0; c < 5; ++c) out[(long)n * 5 + c] = acc[c] * inv + bn[15 + c];
}

// ---------------- launch ----------------
extern "C" void kernel_launch(void* const* d_in, const int* in_sizes, int n_in,
                              void* d_out, int out_size, void* d_ws, size_t ws_size,
                              hipStream_t stream) {
  (void)in_sizes; (void)n_in; (void)out_size; (void)ws_size;
  const float* x   = (const float*)d_in[0];
  const int* eidx  = (const int*)d_in[1];
  const int* esrc  = eidx;
  const int* edst  = eidx + N_EDGES;
  const float* Wq1 = (const float*)d_in[2];  const float* bq1 = (const float*)d_in[3];
  const float* Wk1 = (const float*)d_in[4];  const float* bk1 = (const float*)d_in[5];
  const float* Wv1 = (const float*)d_in[6];  const float* bv1 = (const float*)d_in[7];
  const float* Ws1 = (const float*)d_in[8];  const float* bs1 = (const float*)d_in[9];
  const float* Wq2 = (const float*)d_in[10]; const float* bq2 = (const float*)d_in[11];
  const float* Wk2 = (const float*)d_in[12]; const float* bk2 = (const float*)d_in[13];
  const float* Wv2 = (const float*)d_in[14]; const float* bv2 = (const float*)d_in[15];
  const float* Ws2 = (const float*)d_in[16]; const float* bs2 = (const float*)d_in[17];

  char* p = (char*)d_ws;
  auto take = [&](size_t bytes) { char* r = p; p += (bytes + 255) & ~(size_t)255; return r; };
  unsigned short* xb  = (unsigned short*)take((size_t)NPAD * 384 * 2);
  unsigned short* wbt = (unsigned short*)take((size_t)1024 * 384 * 2);
  float* bias1        = (float*)take(1024 * 4);
  unsigned short* qb  = (unsigned short*)take((size_t)NPAD * 256 * 2);
  unsigned short* kb  = (unsigned short*)take((size_t)NPAD * 256 * 2);
  unsigned short* vb  = (unsigned short*)take((size_t)NPAD * 256 * 2);
  unsigned short* s1b = (unsigned short*)take((size_t)NPAD * 256 * 2);
  float* w2t          = (float*)take(20 * 256 * 4);
  float* bias2        = (float*)take(32 * 4);
  float* qkvs2        = (float*)take((size_t)NPAD * 20 * 4);
  int* counts         = (int*)take((size_t)N_NODES * 4);
  int* offsets        = (int*)take((size_t)(N_NODES + 1) * 4);
  int* cursor         = (int*)take((size_t)N_NODES * 4);
  int* csr_src        = (int*)take((size_t)N_EDGES * 4);
  int* scan_tmp       = (int*)take((size_t)N_NODES * 4);
  int* scan_bsum      = (int*)take(256 * 4);
  int* scan_bbase     = (int*)take(256 * 4);

  hipMemsetAsync(counts, 0, (size_t)N_NODES * 4, stream);
  hist_kernel<<<(N_EDGES + 255) / 256, 256, 0, stream>>>(edst, counts, N_EDGES);
  scan1_kernel<<<SCAN_B, 256, 0, stream>>>(counts, scan_tmp, scan_bsum, N_NODES);
  scan2_kernel<<<1, 256, 0, stream>>>(scan_bsum, scan_bbase, SCAN_B);
  scan3_kernel<<<SCAN_B, 256, 0, stream>>>(scan_tmp, scan_bbase, offsets, cursor, N_NODES, N_EDGES);
  scatter_kernel<<<(N_EDGES + 255) / 256, 256, 0, stream>>>(esrc, edst, cursor, csr_src, N_EDGES);
  convert_x_kernel<<<(NPAD * 384 / 4 + 255) / 256, 256, 0, stream>>>(x, xb, N_NODES * 384, NPAD * 384);
  pack_w1_kernel<<<(1024 * 384 + 255) / 256, 256, 0, stream>>>(Wq1, Wk1, Wv1, Ws1, bq1, bk1, bv1, bs1, wbt, bias1);
  pack_w2_kernel<<<(20 * 256 + 255) / 256, 256, 0, stream>>>(Wq2, Wk2, Wv2, Ws2, bq2, bk2, bv2, bs2, w2t, bias2);
  gemm1_kernel<<<dim3(NPAD / 128, 4), 512, 0, stream>>>(xb, wbt, bias1, qb, kb, vb, s1b);
  agg1_kernel<<<(N_NODES + 3) / 4, 256, 0, stream>>>(qb, kb, vb, s1b, offsets, csr_src);
  lin2_kernel<<<(N_NODES + 3) / 4, 256, 0, stream>>>(s1b, w2t, bias2, qkvs2);
  agg2_kernel<<<(N_NODES + 255) / 256, 256, 0, stream>>>(qkvs2, offsets, csr_src, (float*)d_out);
}